// Round 1
// baseline (15855.151 us; speedup 1.0000x reference)
//
#include <hip/hip_runtime.h>
#include <hip/hip_bf16.h>
#include <stdint.h>

typedef unsigned short u16;
typedef unsigned int   u32;
typedef __bf16 bf16x8 __attribute__((ext_vector_type(8)));
typedef float  f32x4  __attribute__((ext_vector_type(4)));

__device__ __forceinline__ u32 rotl32(u32 v, int d){ return (v<<d)|(v>>(32-d)); }

// JAX threefry2x32: 20 rounds
__device__ __forceinline__ void tf2x32(u32 k0, u32 k1, u32 c0, u32 c1, u32 &o0, u32 &o1){
  u32 ks0=k0, ks1=k1, ks2=k0^k1^0x1BD11BDAu;
  u32 x0=c0+ks0, x1=c1+ks1;
  x0+=x1; x1=rotl32(x1,13); x1^=x0;  x0+=x1; x1=rotl32(x1,15); x1^=x0;
  x0+=x1; x1=rotl32(x1,26); x1^=x0;  x0+=x1; x1=rotl32(x1, 6); x1^=x0;
  x0+=ks1; x1+=ks2+1u;
  x0+=x1; x1=rotl32(x1,17); x1^=x0;  x0+=x1; x1=rotl32(x1,29); x1^=x0;
  x0+=x1; x1=rotl32(x1,16); x1^=x0;  x0+=x1; x1=rotl32(x1,24); x1^=x0;
  x0+=ks2; x1+=ks0+2u;
  x0+=x1; x1=rotl32(x1,13); x1^=x0;  x0+=x1; x1=rotl32(x1,15); x1^=x0;
  x0+=x1; x1=rotl32(x1,26); x1^=x0;  x0+=x1; x1=rotl32(x1, 6); x1^=x0;
  x0+=ks0; x1+=ks1+3u;
  x0+=x1; x1=rotl32(x1,17); x1^=x0;  x0+=x1; x1=rotl32(x1,29); x1^=x0;
  x0+=x1; x1=rotl32(x1,16); x1^=x0;  x0+=x1; x1=rotl32(x1,24); x1^=x0;
  x0+=ks1; x1+=ks2+4u;
  x0+=x1; x1=rotl32(x1,13); x1^=x0;  x0+=x1; x1=rotl32(x1,15); x1^=x0;
  x0+=x1; x1=rotl32(x1,26); x1^=x0;  x0+=x1; x1=rotl32(x1, 6); x1^=x0;
  x0+=ks2; x1+=ks0+5u;
  o0=x0; o1=x1;
}

__device__ __forceinline__ float u01(u32 b){ return __uint_as_float((b>>9)|0x3f800000u) - 1.0f; }
__device__ __forceinline__ u16 f2bf(float v){ __hip_bfloat16 h = __float2bfloat16(v); return *reinterpret_cast<u16*>(&h); }
__device__ __forceinline__ float bf2f(u16 b){ __hip_bfloat16 h; *reinterpret_cast<u16*>(&h)=b; return __bfloat162float(h); }
__device__ __forceinline__ float sigm(float x){ return 1.0f/(1.0f + __expf(-x)); }
__device__ __forceinline__ float tanh_f(float x){ return 1.0f - 2.0f/(__expf(2.0f*x) + 1.0f); }

// ---- kernel 1: weight packing (4 mats) + flag/code zero + PARTITIONABLE root split + KAT ----
// mats: 0=WxHi 1=WhHi 2=WhLo 3=WxLo
// idx = (((dir*32+ug)*16 + kt)*4 + gt)*4 + mat ; lane supplies B[k=kt*32+(lane>>4)*8+j][col=gt*512+ug*16+(lane&15)]
extern "C" __global__ void __launch_bounds__(256) prep_k(
    const float* __restrict__ Wf, const float* __restrict__ Wb,
    u16* __restrict__ wpack, u32* __restrict__ flags, u32* __restrict__ code, u32* __restrict__ keys){
  u32 gid = blockIdx.x*256u + threadIdx.x;
  if (gid < 8192u) flags[gid] = 0u;
  if (gid == 0u){
    *code = 0u;
    // jax_threefry_partitionable (default since JAX 0.5): split is "foldlike" —
    // child i of key K = full output pair of threefry(K, (0, i)).
    u32 d0,d1,f0,f1,g0,g1;
    tf2x32(0u,42u, 0u,0u, d0,d1);   // kd = split(key(42),3)[0]
    tf2x32(0u,42u, 0u,1u, f0,f1);   // kf = [1]
    tf2x32(0u,42u, 0u,2u, g0,g1);   // kb = [2]
    keys[0]=d0; keys[1]=d1; keys[2]=f0; keys[3]=f1; keys[4]=g0; keys[5]=g1;
  }
  if (gid == 1u){
    // Known-answer test (Random123 / jax tests/random_test.py testThreefry2x32)
    u32 r0,r1; bool ok = true;
    tf2x32(0u,0u,0u,0u,r0,r1);
    ok = ok && (r0==0x6b200159u) && (r1==0x99ba4efeu);
    tf2x32(0x13198a2eu,0x03707344u,0x243f6a88u,0x85a308d3u,r0,r1);
    ok = ok && (r0==0xc4923a9cu) && (r1==0x483df7a0u);
    tf2x32(0xffffffffu,0xffffffffu,0xffffffffu,0xffffffffu,r0,r1);
    ok = ok && (r0==0x1cb996fcu) && (r1==0xbb002be7u);
    if (!ok) __hip_atomic_fetch_or(code, 4u, __ATOMIC_RELAXED, __HIP_MEMORY_SCOPE_AGENT);
  }
  u32 idx = gid >> 6, lane = gid & 63u;
  u32 mat = idx & 3u; u32 r = idx >> 2;
  u32 gt = r & 3u; r >>= 2;
  u32 kt = r & 15u; r >>= 4;
  u32 ug = r & 31u; u32 dir = r >> 5;
  u32 col = gt*512u + ug*16u + (lane & 15u);
  u32 kb  = kt*32u + ((lane>>4)<<3);
  const float* W = dir ? Wb : Wf;
  bool hrow = (mat==1u || mat==2u);
  bool lo   = (mat==2u || mat==3u);
  u16 o[8];
  #pragma unroll
  for (int j=0;j<8;j++){
    u32 k = kb + (u32)j;
    u32 row = hrow ? (512u + k) : k;
    float v = W[(size_t)row*2048u + col];
    u16 h = f2bf(v);
    o[j] = lo ? f2bf(v - bf2f(h)) : h;
  }
  u16* dst = wpack + ((size_t)idx*64u + lane)*8u;
  uint4 pk;
  pk.x = (u32)o[0] | ((u32)o[1]<<16);
  pk.y = (u32)o[2] | ((u32)o[3]<<16);
  pk.z = (u32)o[4] | ((u32)o[5]<<16);
  pk.w = (u32)o[6] | ((u32)o[7]<<16);
  *(uint4*)dst = pk;
}

// ---- kernel 2: embedding + dropout, PARTITIONABLE bits: elem i gets o0^o1 of tf(kd,(0,i)) ----
extern "C" __global__ void __launch_bounds__(256) embed_k(
    const int* __restrict__ tokens, const float* __restrict__ emb,
    const u32* __restrict__ keys, u16* __restrict__ X, u16* __restrict__ XLO, int xsplit){
  u32 gid = blockIdx.x*256u + threadIdx.x;   // 2^24 threads, 2 elems each (adjacent d)
  u32 kd0 = keys[0], kd1 = keys[1];
  u32 i0 = gid << 1;
  u32 a0,a1,b0,b1;
  tf2x32(kd0,kd1, 0u, i0,     a0,a1);
  tf2x32(kd0,kd1, 0u, i0|1u,  b0,b1);
  u32 bb = i0 >> 19, l = (i0 >> 9) & 1023u, d = i0 & 511u;   // d even
  int tok = tokens[(bb<<10)|l];
  const float* ep = emb + (size_t)(u32)tok*512u + d;
  float e0 = ep[0], e1 = ep[1];
  float v0 = (u01(a0^a1) < 0.9f) ? (e0/0.9f) : 0.0f;
  float v1 = (u01(b0^b1) < 0.9f) ? (e1/0.9f) : 0.0f;
  size_t off = (((size_t)l<<6)|bb)*512u + d;
  u16 h0 = f2bf(v0), h1 = f2bf(v1);
  *(u32*)(X+off) = (u32)h0 | ((u32)h1<<16);
  if (xsplit){
    u16 l0 = f2bf(v0 - bf2f(h0)), l1 = f2bf(v1 - bf2f(h1));
    *(u32*)(XLO+off) = (u32)l0 | ((u32)l1<<16);
  }
}

// ---- kernel 3: persistent bidirectional LSTM, phase-split step loop ----
// Phase A (independent of peers): zoneout key chain, x staging, zoneout RNG bits, x-part MFMAs.
// Phase B (after flag wait): acquire-fence (buffer_inv) + cached vector h loads, h-part MFMAs.
// Phase C: reduce partials, cell update (c/h in registers), publish h + flag.
extern "C" __global__ void __launch_bounds__(256,1) lstm_k(
    const u16* __restrict__ wpack, const u16* __restrict__ X, const u16* __restrict__ XLO,
    u32* hbuf, u32* chk, u32* flags, u32* code, const u32* __restrict__ keys,
    const int* __restrict__ lengths, const float* __restrict__ bF, const float* __restrict__ bB,
    float* __restrict__ out, int xsplit){
  __shared__ u16 xHi[16][520];
  __shared__ u16 xLoS[16][520];
  __shared__ u16 hHi[16][520];
  __shared__ u16 hLo[16][520];
  __shared__ float gparts[4][4][16][16];
  __shared__ u32 kzS[2];
  (void)chk;

  const int tid  = threadIdx.x;
  const int wid  = tid >> 6;
  const int lane = tid & 63;
  const int q    = lane >> 4, n15 = lane & 15;
  const int bx   = blockIdx.x;
  const int dir  = (bx & 7) >> 2, bg = bx & 3, ug = bx >> 3;
  const int grp  = dir*4 + bg;
  const int eb   = tid >> 4, eu = tid & 15;
  const int scol = eu * 32;

  // ---- self-test: MFMA A/B/C-D layout (bx0, wave0) ----
  if (bx == 0 && wid == 0){
    bf16x8 aI, aI2, bT;
    #pragma unroll
    for (int j=0;j<8;j++){
      int k = q*8 + j;
      aI[j]  = (__bf16)((k == n15)    ? 1.0f : 0.0f);
      aI2[j] = (__bf16)((k == n15+16) ? 1.0f : 0.0f);
      bT[j]  = (__bf16)((float)((k & 15)*16 + n15));
    }
    f32x4 z = {0.0f,0.0f,0.0f,0.0f};
    f32x4 d1 = __builtin_amdgcn_mfma_f32_16x16x32_bf16(aI,  bT, z, 0,0,0);
    f32x4 d2 = __builtin_amdgcn_mfma_f32_16x16x32_bf16(aI2, bT, z, 0,0,0);
    bool ok = true;
    #pragma unroll
    for (int r=0;r<4;r++){
      float ex = (float)((q*4 + r)*16 + n15);
      ok = ok && (d1[r] == ex) && (d2[r] == ex);
    }
    if (__any(ok ? 0 : 1) && lane == 0)
      __hip_atomic_fetch_or(code, 1u, __ATOMIC_RELAXED, __HIP_MEMORY_SCOPE_AGENT);
  }

  u32 kc0 = keys[2 + dir*2], kc1 = keys[3 + dir*2];

  bf16x8 BW[4][4][4];   // [mat][ktl][gt]  0=WxHi 1=WhHi 2=WhLo 3=WxLo
  #pragma unroll
  for (int ktl=0;ktl<4;ktl++)
    #pragma unroll
    for (int gt=0;gt<4;gt++)
      #pragma unroll
      for (int mat=0;mat<4;mat++){
        size_t idx = ((((size_t)(dir*32+ug)*16 + (size_t)(wid*4+ktl))*4 + gt)*4 + mat);
        BW[mat][ktl][gt] = *(const bf16x8*)(wpack + (idx*64 + lane)*8);
      }

  const float* bias = dir ? bB : bF;
  float biasr[4];
  #pragma unroll
  for (int g=0;g<4;g++) biasr[g] = bias[g*512 + ug*16 + eu];
  const int lenb = lengths[bg*16 + eb];

  float cReg = 0.0f, hReg = 0.0f;   // per-(eb,eu) cell state lives in registers

  u32* myfl = flags + grp*1024;
  u32* hb_base = hbuf + (size_t)grp*2*16*512;
  const size_t outbase = (size_t)(bg*16+eb)*1048576 + (size_t)(dir*512 + ug*16 + eu);

  for (int t=0; t<1024; ++t){
    // ================= phase A: no cross-block dependencies =================
    // zoneout key chain (wave0 owns it; kz broadcast via LDS under the stage sync)
    if (wid == 0){
      u32 A0,A1,B0,B1;
      tf2x32(kc0,kc1, 0u,0u, A0,A1);
      tf2x32(kc0,kc1, 0u,1u, B0,B1);
      if (lane==0){ kzS[0]=A0; kzS[1]=A1; }
      kc0=B0; kc1=B1;
    }
    // stage x_t
    const int tx = dir ? (1023 - t) : t;
    {
      size_t xoff = (((size_t)tx*64) + (size_t)(bg*16 + eb))*512 + scol;
      const uint4* xs = (const uint4*)(X + xoff);
      uint4* xd = (uint4*)&xHi[eb][scol];
      xd[0]=xs[0]; xd[1]=xs[1]; xd[2]=xs[2]; xd[3]=xs[3];
      if (xsplit){
        const uint4* ls = (const uint4*)(XLO + xoff);
        uint4* ld = (uint4*)&xLoS[eb][scol];
        ld[0]=ls[0]; ld[1]=ls[1]; ld[2]=ls[2]; ld[3]=ls[3];
      }
    }
    __syncthreads();   // x staged + kzS visible

    // zoneout bits for this step (VALU; scheduler interleaves with x-MFMAs below)
    const u32 cnt = (u32)((bg*16+eb)*512 + ug*16+eu);
    u32 p0,p1,q0,q1;
    tf2x32(kzS[0], kzS[1], 0u, cnt,          p0,p1);
    tf2x32(kzS[0], kzS[1], 0u, cnt+32768u,   q0,q1);
    const bool keepH = (u01(p0^p1) < 0.1f);
    const bool keepC = (u01(q0^q1) < 0.1f);

    // x-part MFMAs: xHi*WxHi + xHi*WxLo (+ xLo*WxHi)
    f32x4 zz = {0.0f,0.0f,0.0f,0.0f};
    f32x4 acc[4] = {zz,zz,zz,zz};
    #pragma unroll
    for (int ktl=0;ktl<4;ktl++){
      const int ko = (wid*4+ktl)*32 + q*8;
      bf16x8 ax = *(const bf16x8*)&xHi[n15][ko];
      #pragma unroll
      for (int gt=0;gt<4;gt++){
        acc[gt] = __builtin_amdgcn_mfma_f32_16x16x32_bf16(ax, BW[0][ktl][gt], acc[gt], 0,0,0);
        acc[gt] = __builtin_amdgcn_mfma_f32_16x16x32_bf16(ax, BW[3][ktl][gt], acc[gt], 0,0,0);
      }
      if (xsplit){
        bf16x8 axl = *(const bf16x8*)&xLoS[n15][ko];
        #pragma unroll
        for (int gt=0;gt<4;gt++)
          acc[gt] = __builtin_amdgcn_mfma_f32_16x16x32_bf16(axl, BW[0][ktl][gt], acc[gt], 0,0,0);
      }
    }

    // ================= phase B: wait for peers' h(t-1), stage it =================
    const bool rst = (dir==1) && (t > 1024 - lenb);
    if (t > 0){
      if (tid == 0){
        while (__hip_atomic_load(myfl + (t-1), __ATOMIC_RELAXED, __HIP_MEMORY_SCOPE_AGENT) < 32u)
          __builtin_amdgcn_s_sleep(1);
      }
      __syncthreads();
      // acquire: invalidate stale L1/L2 lines so plain vector loads see the
      // peers' write-through (agent-scope) h stores.
      __builtin_amdgcn_fence(__ATOMIC_ACQUIRE, "agent");
    }
    if (t == 0 || rst){
      uint4 z; z.x=0u; z.y=0u; z.z=0u; z.w=0u;
      uint4* hd = (uint4*)&hHi[eb][scol];
      uint4* ld = (uint4*)&hLo[eb][scol];
      hd[0]=z;hd[1]=z;hd[2]=z;hd[3]=z;  ld[0]=z;ld[1]=z;ld[2]=z;ld[3]=z;
    } else {
      const u32* hrow = hb_base + ((size_t)((t-1)&1)*16 + eb)*512 + scol;
      uint4 hv4[8];
      #pragma unroll
      for (int v=0;v<8;v++) hv4[v] = ((const uint4*)hrow)[v];
      u32 hv[32];
      #pragma unroll
      for (int v=0;v<8;v++){
        hv[4*v+0]=hv4[v].x; hv[4*v+1]=hv4[v].y; hv[4*v+2]=hv4[v].z; hv[4*v+3]=hv4[v].w;
      }
      u32 hiw[16], low[16];
      #pragma unroll
      for (int k=0;k<16;k++){
        hiw[k] = (hv[2*k] & 0xFFFFu) | (hv[2*k+1] << 16);
        low[k] = (hv[2*k] >> 16)     | (hv[2*k+1] & 0xFFFF0000u);
      }
      uint4* hd = (uint4*)&hHi[eb][scol];
      uint4* ld = (uint4*)&hLo[eb][scol];
      #pragma unroll
      for (int v=0;v<4;v++){
        uint4 hw; hw.x=hiw[4*v]; hw.y=hiw[4*v+1]; hw.z=hiw[4*v+2]; hw.w=hiw[4*v+3];
        uint4 lw; lw.x=low[4*v]; lw.y=low[4*v+1]; lw.z=low[4*v+2]; lw.w=low[4*v+3];
        hd[v]=hw; ld[v]=lw;
      }
    }
    __syncthreads();

    // h-part MFMAs: hHi*WhHi + hHi*WhLo + hLo*WhHi
    #pragma unroll
    for (int ktl=0;ktl<4;ktl++){
      const int ko = (wid*4+ktl)*32 + q*8;
      bf16x8 ahi = *(const bf16x8*)&hHi[n15][ko];
      bf16x8 alo = *(const bf16x8*)&hLo[n15][ko];
      #pragma unroll
      for (int gt=0;gt<4;gt++){
        acc[gt] = __builtin_amdgcn_mfma_f32_16x16x32_bf16(ahi, BW[1][ktl][gt], acc[gt], 0,0,0);
        acc[gt] = __builtin_amdgcn_mfma_f32_16x16x32_bf16(ahi, BW[2][ktl][gt], acc[gt], 0,0,0);
        acc[gt] = __builtin_amdgcn_mfma_f32_16x16x32_bf16(alo, BW[1][ktl][gt], acc[gt], 0,0,0);
      }
    }
    #pragma unroll
    for (int gt=0;gt<4;gt++)
      #pragma unroll
      for (int r=0;r<4;r++)
        gparts[wid][gt][q*4+r][n15] = acc[gt][r];
    __syncthreads();

    // ================= phase C: cell update + publish =================
    float gv[4];
    #pragma unroll
    for (int g=0;g<4;g++)
      gv[g] = gparts[0][g][eb][eu]+gparts[1][g][eb][eu]+gparts[2][g][eb][eu]+gparts[3][g][eb][eu]+biasr[g];
    float cp = cReg, hprev = hReg;
    if (rst){ cp = 0.0f; hprev = 0.0f; }
    float fg = sigm(gv[2] + 1.0f);
    float cn = fg*cp + sigm(gv[0])*tanh_f(gv[1]);
    float hn = sigm(gv[3])*tanh_f(cn);
    float ho = keepH ? hprev : hn;
    float co = keepC ? cp    : cn;
    cReg = co; hReg = ho;
    out[outbase + ((size_t)tx << 10)] = ho;
    u16 hhi = f2bf(ho); u16 hlo = f2bf(ho - bf2f(hhi));
    u32 hp32 = ((u32)hlo<<16) | (u32)hhi;
    __hip_atomic_store(hb_base + ((size_t)(t&1)*16 + eb)*512 + (size_t)(ug*16+eu), hp32,
                       __ATOMIC_RELAXED, __HIP_MEMORY_SCOPE_AGENT);
    __syncthreads();   // all 256 h stores complete (vmcnt drained) before flag
    if (tid == 0)
      __hip_atomic_fetch_add(myfl + t, 1u, __ATOMIC_RELEASE, __HIP_MEMORY_SCOPE_AGENT);
  }

  // ---- diagnostic channel: out[0] = 1000*code iff any self-test fired ----
  if (bx == 0 && tid == 0){
    u32 c = __hip_atomic_load(code, __ATOMIC_ACQUIRE, __HIP_MEMORY_SCOPE_AGENT);
    if (c != 0u) out[0] = 1000.0f * (float)c;
  }
}

extern "C" void kernel_launch(void* const* d_in, const int* in_sizes, int n_in,
                              void* d_out, int out_size, void* d_ws, size_t ws_size,
                              hipStream_t stream) {
  const int*   tokens  = (const int*)d_in[0];
  const int*   lengths = (const int*)d_in[1];
  const float* embed   = (const float*)d_in[2];
  const float* Wf      = (const float*)d_in[3];
  const float* bF      = (const float*)d_in[4];
  const float* Wb      = (const float*)d_in[5];
  const float* bB      = (const float*)d_in[6];
  float* out = (float*)d_out;

  const size_t SZ_WPACK = 16777216ull;
  const size_t SZ_X     = 67108864ull;
  const size_t SZ_HBUF  = 524288ull;
  const size_t SZ_CHK   = 65536ull;
  const size_t SZ_FLAGS = 32768ull;
  size_t need_full = SZ_WPACK + 2*SZ_X + SZ_HBUF + SZ_CHK + SZ_FLAGS + 128;
  int xsplit = (ws_size >= need_full) ? 1 : 0;

  char* p = (char*)d_ws;
  u16* wpack = (u16*)p;            p += SZ_WPACK;
  u16* X     = (u16*)p;            p += SZ_X;
  u16* XLO   = xsplit ? (u16*)p : X;
  if (xsplit)                      p += SZ_X;
  u32* hbuf  = (u32*)p;            p += SZ_HBUF;
  u32* chk   = (u32*)p;            p += SZ_CHK;
  u32* flags = (u32*)p;            p += SZ_FLAGS;
  u32* code  = (u32*)p;            p += 64;
  u32* keys  = (u32*)p;

  prep_k<<<dim3(4096), dim3(256), 0, stream>>>(Wf, Wb, wpack, flags, code, keys);
  embed_k<<<dim3(65536), dim3(256), 0, stream>>>(tokens, embed, keys, X, XLO, xsplit);
  lstm_k<<<dim3(256), dim3(256), 0, stream>>>(wpack, X, XLO, hbuf, chk, flags, code, keys,
                                              lengths, bF, bB, out, xsplit);
}

// Round 2
// 8177.963 us; speedup vs baseline: 1.9388x; 1.9388x over previous
//
#include <hip/hip_runtime.h>
#include <hip/hip_bf16.h>
#include <stdint.h>

typedef unsigned short u16;
typedef unsigned int   u32;
typedef unsigned long long u64;
typedef __bf16 bf16x8 __attribute__((ext_vector_type(8)));
typedef float  f32x4  __attribute__((ext_vector_type(4)));

__device__ __forceinline__ u32 rotl32(u32 v, int d){ return (v<<d)|(v>>(32-d)); }

// JAX threefry2x32: 20 rounds
__device__ __forceinline__ void tf2x32(u32 k0, u32 k1, u32 c0, u32 c1, u32 &o0, u32 &o1){
  u32 ks0=k0, ks1=k1, ks2=k0^k1^0x1BD11BDAu;
  u32 x0=c0+ks0, x1=c1+ks1;
  x0+=x1; x1=rotl32(x1,13); x1^=x0;  x0+=x1; x1=rotl32(x1,15); x1^=x0;
  x0+=x1; x1=rotl32(x1,26); x1^=x0;  x0+=x1; x1=rotl32(x1, 6); x1^=x0;
  x0+=ks1; x1+=ks2+1u;
  x0+=x1; x1=rotl32(x1,17); x1^=x0;  x0+=x1; x1=rotl32(x1,29); x1^=x0;
  x0+=x1; x1=rotl32(x1,16); x1^=x0;  x0+=x1; x1=rotl32(x1,24); x1^=x0;
  x0+=ks2; x1+=ks0+2u;
  x0+=x1; x1=rotl32(x1,13); x1^=x0;  x0+=x1; x1=rotl32(x1,15); x1^=x0;
  x0+=x1; x1=rotl32(x1,26); x1^=x0;  x0+=x1; x1=rotl32(x1, 6); x1^=x0;
  x0+=ks0; x1+=ks1+3u;
  x0+=x1; x1=rotl32(x1,17); x1^=x0;  x0+=x1; x1=rotl32(x1,29); x1^=x0;
  x0+=x1; x1=rotl32(x1,16); x1^=x0;  x0+=x1; x1=rotl32(x1,24); x1^=x0;
  x0+=ks1; x1+=ks2+4u;
  x0+=x1; x1=rotl32(x1,13); x1^=x0;  x0+=x1; x1=rotl32(x1,15); x1^=x0;
  x0+=x1; x1=rotl32(x1,26); x1^=x0;  x0+=x1; x1=rotl32(x1, 6); x1^=x0;
  x0+=ks2; x1+=ks0+5u;
  o0=x0; o1=x1;
}

__device__ __forceinline__ float u01(u32 b){ return __uint_as_float((b>>9)|0x3f800000u) - 1.0f; }
__device__ __forceinline__ u16 f2bf(float v){ __hip_bfloat16 h = __float2bfloat16(v); return *reinterpret_cast<u16*>(&h); }
__device__ __forceinline__ float bf2f(u16 b){ __hip_bfloat16 h; *reinterpret_cast<u16*>(&h)=b; return __bfloat162float(h); }
__device__ __forceinline__ float sigm(float x){ return 1.0f/(1.0f + __expf(-x)); }
__device__ __forceinline__ float tanh_f(float x){ return 1.0f - 2.0f/(__expf(2.0f*x) + 1.0f); }

// ---- kernel 1: weight packing (4 mats) + flag/code zero + PARTITIONABLE root split + KAT ----
// mats: 0=WxHi 1=WhHi 2=WhLo 3=WxLo
// idx = (((dir*32+ug)*16 + kt)*4 + gt)*4 + mat ; lane supplies B[k=kt*32+(lane>>4)*8+j][col=gt*512+ug*16+(lane&15)]
extern "C" __global__ void __launch_bounds__(256) prep_k(
    const float* __restrict__ Wf, const float* __restrict__ Wb,
    u16* __restrict__ wpack, u32* __restrict__ flags, u32* __restrict__ code, u32* __restrict__ keys){
  u32 gid = blockIdx.x*256u + threadIdx.x;
  if (gid < 8192u) flags[gid] = 0u;
  if (gid == 0u){
    *code = 0u;
    // jax_threefry_partitionable (default since JAX 0.5): split is "foldlike" —
    // child i of key K = full output pair of threefry(K, (0, i)).
    u32 d0,d1,f0,f1,g0,g1;
    tf2x32(0u,42u, 0u,0u, d0,d1);   // kd = split(key(42),3)[0]
    tf2x32(0u,42u, 0u,1u, f0,f1);   // kf = [1]
    tf2x32(0u,42u, 0u,2u, g0,g1);   // kb = [2]
    keys[0]=d0; keys[1]=d1; keys[2]=f0; keys[3]=f1; keys[4]=g0; keys[5]=g1;
  }
  if (gid == 1u){
    // Known-answer test (Random123 / jax tests/random_test.py testThreefry2x32)
    u32 r0,r1; bool ok = true;
    tf2x32(0u,0u,0u,0u,r0,r1);
    ok = ok && (r0==0x6b200159u) && (r1==0x99ba4efeu);
    tf2x32(0x13198a2eu,0x03707344u,0x243f6a88u,0x85a308d3u,r0,r1);
    ok = ok && (r0==0xc4923a9cu) && (r1==0x483df7a0u);
    tf2x32(0xffffffffu,0xffffffffu,0xffffffffu,0xffffffffu,r0,r1);
    ok = ok && (r0==0x1cb996fcu) && (r1==0xbb002be7u);
    if (!ok) __hip_atomic_fetch_or(code, 4u, __ATOMIC_RELAXED, __HIP_MEMORY_SCOPE_AGENT);
  }
  u32 idx = gid >> 6, lane = gid & 63u;
  u32 mat = idx & 3u; u32 r = idx >> 2;
  u32 gt = r & 3u; r >>= 2;
  u32 kt = r & 15u; r >>= 4;
  u32 ug = r & 31u; u32 dir = r >> 5;
  u32 col = gt*512u + ug*16u + (lane & 15u);
  u32 kb  = kt*32u + ((lane>>4)<<3);
  const float* W = dir ? Wb : Wf;
  bool hrow = (mat==1u || mat==2u);
  bool lo   = (mat==2u || mat==3u);
  u16 o[8];
  #pragma unroll
  for (int j=0;j<8;j++){
    u32 k = kb + (u32)j;
    u32 row = hrow ? (512u + k) : k;
    float v = W[(size_t)row*2048u + col];
    u16 h = f2bf(v);
    o[j] = lo ? f2bf(v - bf2f(h)) : h;
  }
  u16* dst = wpack + ((size_t)idx*64u + lane)*8u;
  uint4 pk;
  pk.x = (u32)o[0] | ((u32)o[1]<<16);
  pk.y = (u32)o[2] | ((u32)o[3]<<16);
  pk.z = (u32)o[4] | ((u32)o[5]<<16);
  pk.w = (u32)o[6] | ((u32)o[7]<<16);
  *(uint4*)dst = pk;
}

// ---- kernel 2: embedding + dropout, PARTITIONABLE bits: elem i gets o0^o1 of tf(kd,(0,i)) ----
extern "C" __global__ void __launch_bounds__(256) embed_k(
    const int* __restrict__ tokens, const float* __restrict__ emb,
    const u32* __restrict__ keys, u16* __restrict__ X, u16* __restrict__ XLO, int xsplit){
  u32 gid = blockIdx.x*256u + threadIdx.x;   // 2^24 threads, 2 elems each (adjacent d)
  u32 kd0 = keys[0], kd1 = keys[1];
  u32 i0 = gid << 1;
  u32 a0,a1,b0,b1;
  tf2x32(kd0,kd1, 0u, i0,     a0,a1);
  tf2x32(kd0,kd1, 0u, i0|1u,  b0,b1);
  u32 bb = i0 >> 19, l = (i0 >> 9) & 1023u, d = i0 & 511u;   // d even
  int tok = tokens[(bb<<10)|l];
  const float* ep = emb + (size_t)(u32)tok*512u + d;
  float e0 = ep[0], e1 = ep[1];
  float v0 = (u01(a0^a1) < 0.9f) ? (e0/0.9f) : 0.0f;
  float v1 = (u01(b0^b1) < 0.9f) ? (e1/0.9f) : 0.0f;
  size_t off = (((size_t)l<<6)|bb)*512u + d;
  u16 h0 = f2bf(v0), h1 = f2bf(v1);
  *(u32*)(X+off) = (u32)h0 | ((u32)h1<<16);
  if (xsplit){
    u16 l0 = f2bf(v0 - bf2f(h0)), l1 = f2bf(v1 - bf2f(h1));
    *(u32*)(XLO+off) = (u32)l0 | ((u32)l1<<16);
  }
}

// ---- kernel 3: persistent bidirectional LSTM ----
// ZERO cache-maintenance protocol: all cross-block data moves via agent-scope
// RELAXED atomics (sc0 sc1 — write-through / cache-bypass, coherent at LLC).
// No acquire fences (no buffer_inv), no release RMW (no buffer_wbl2).
//  - h transport: relaxed u64 atomic loads (always read LLC).
//  - completion: per-block stamp word, relaxed atomic store of (t+1) AFTER the
//    vmcnt-draining __syncthreads (h stores are write-through, so vmcnt retire
//    == LLC visibility). Consumers poll all 32 stamps with 32 parallel lanes.
//  - slot protection: stamp >= t  ==>  peer finished step t-1  ==>  peer has
//    read h(t-2), so writing slot t&1 = (t-2)&1 is safe. Same invariant as the
//    old counting flag.
extern "C" __global__ void __launch_bounds__(256,1) lstm_k(
    const u16* __restrict__ wpack, const u16* __restrict__ X, const u16* __restrict__ XLO,
    u32* hbuf, u32* chk, u32* flags, u32* code, const u32* __restrict__ keys,
    const int* __restrict__ lengths, const float* __restrict__ bF, const float* __restrict__ bB,
    float* __restrict__ out, int xsplit){
  __shared__ u16 xHi[16][520];
  __shared__ u16 xLoS[16][520];
  __shared__ u16 hHi[16][520];
  __shared__ u16 hLo[16][520];
  __shared__ float gparts[4][4][16][17];   // padded: 4-way -> 2-way bank conflicts
  __shared__ u32 kzS[2];
  (void)chk;

  const int tid  = threadIdx.x;
  const int wid  = tid >> 6;
  const int lane = tid & 63;
  const int q    = lane >> 4, n15 = lane & 15;
  const int bx   = blockIdx.x;
  const int dir  = (bx & 7) >> 2, bg = bx & 3, ug = bx >> 3;
  const int grp  = dir*4 + bg;
  const int eb   = tid >> 4, eu = tid & 15;
  const int scol = eu * 32;

  // ---- self-test: MFMA A/B/C-D layout (bx0, wave0) ----
  if (bx == 0 && wid == 0){
    bf16x8 aI, aI2, bT;
    #pragma unroll
    for (int j=0;j<8;j++){
      int k = q*8 + j;
      aI[j]  = (__bf16)((k == n15)    ? 1.0f : 0.0f);
      aI2[j] = (__bf16)((k == n15+16) ? 1.0f : 0.0f);
      bT[j]  = (__bf16)((float)((k & 15)*16 + n15));
    }
    f32x4 z = {0.0f,0.0f,0.0f,0.0f};
    f32x4 d1 = __builtin_amdgcn_mfma_f32_16x16x32_bf16(aI,  bT, z, 0,0,0);
    f32x4 d2 = __builtin_amdgcn_mfma_f32_16x16x32_bf16(aI2, bT, z, 0,0,0);
    bool ok = true;
    #pragma unroll
    for (int r=0;r<4;r++){
      float ex = (float)((q*4 + r)*16 + n15);
      ok = ok && (d1[r] == ex) && (d2[r] == ex);
    }
    if (__any(ok ? 0 : 1) && lane == 0)
      __hip_atomic_fetch_or(code, 1u, __ATOMIC_RELAXED, __HIP_MEMORY_SCOPE_AGENT);
  }

  u32 kc0 = keys[2 + dir*2], kc1 = keys[3 + dir*2];

  bf16x8 BW[4][4][4];   // [mat][ktl][gt]  0=WxHi 1=WhHi 2=WhLo 3=WxLo
  #pragma unroll
  for (int ktl=0;ktl<4;ktl++)
    #pragma unroll
    for (int gt=0;gt<4;gt++)
      #pragma unroll
      for (int mat=0;mat<4;mat++){
        size_t idx = ((((size_t)(dir*32+ug)*16 + (size_t)(wid*4+ktl))*4 + gt)*4 + mat);
        BW[mat][ktl][gt] = *(const bf16x8*)(wpack + (idx*64 + lane)*8);
      }

  const float* bias = dir ? bB : bF;
  float biasr[4];
  #pragma unroll
  for (int g=0;g<4;g++) biasr[g] = bias[g*512 + ug*16 + eu];
  const int lenb = lengths[bg*16 + eb];

  float cReg = 0.0f, hReg = 0.0f;   // per-(eb,eu) cell state in registers

  u32* stamps = flags + grp*32;                 // one word per ug-block in this group
  u32* hb_base = hbuf + (size_t)grp*2*16*512;
  const size_t outbase = (size_t)(bg*16+eb)*1048576 + (size_t)(dir*512 + ug*16 + eu);

  for (int t=0; t<1024; ++t){
    // ================= phase A: no cross-block dependencies =================
    if (wid == 0){
      u32 A0,A1,B0,B1;
      tf2x32(kc0,kc1, 0u,0u, A0,A1);
      tf2x32(kc0,kc1, 0u,1u, B0,B1);
      if (lane==0){ kzS[0]=A0; kzS[1]=A1; }
      kc0=B0; kc1=B1;
    }
    const int tx = dir ? (1023 - t) : t;
    {
      size_t xoff = (((size_t)tx*64) + (size_t)(bg*16 + eb))*512 + scol;
      const uint4* xs = (const uint4*)(X + xoff);
      uint4* xd = (uint4*)&xHi[eb][scol];
      xd[0]=xs[0]; xd[1]=xs[1]; xd[2]=xs[2]; xd[3]=xs[3];
      if (xsplit){
        const uint4* ls = (const uint4*)(XLO + xoff);
        uint4* ld = (uint4*)&xLoS[eb][scol];
        ld[0]=ls[0]; ld[1]=ls[1]; ld[2]=ls[2]; ld[3]=ls[3];
      }
    }
    __syncthreads();   // x staged + kzS visible

    // zoneout bits for this step
    const u32 cnt = (u32)((bg*16+eb)*512 + ug*16+eu);
    u32 p0,p1,q0,q1;
    tf2x32(kzS[0], kzS[1], 0u, cnt,          p0,p1);
    tf2x32(kzS[0], kzS[1], 0u, cnt+32768u,   q0,q1);
    const bool keepH = (u01(p0^p1) < 0.1f);
    const bool keepC = (u01(q0^q1) < 0.1f);

    // x-part MFMAs: xHi*WxHi + xHi*WxLo (+ xLo*WxHi)
    f32x4 zz = {0.0f,0.0f,0.0f,0.0f};
    f32x4 acc[4] = {zz,zz,zz,zz};
    #pragma unroll
    for (int ktl=0;ktl<4;ktl++){
      const int ko = (wid*4+ktl)*32 + q*8;
      bf16x8 ax = *(const bf16x8*)&xHi[n15][ko];
      #pragma unroll
      for (int gt=0;gt<4;gt++){
        acc[gt] = __builtin_amdgcn_mfma_f32_16x16x32_bf16(ax, BW[0][ktl][gt], acc[gt], 0,0,0);
        acc[gt] = __builtin_amdgcn_mfma_f32_16x16x32_bf16(ax, BW[3][ktl][gt], acc[gt], 0,0,0);
      }
      if (xsplit){
        bf16x8 axl = *(const bf16x8*)&xLoS[n15][ko];
        #pragma unroll
        for (int gt=0;gt<4;gt++)
          acc[gt] = __builtin_amdgcn_mfma_f32_16x16x32_bf16(axl, BW[0][ktl][gt], acc[gt], 0,0,0);
      }
    }

    // ================= phase B: wait for peers' step t-1, stage h(t-1) =================
    const bool rst = (dir==1) && (t > 1024 - lenb);
    if (t > 0){
      if (tid < 32){
        const u32* sp = stamps + tid;
        while (__hip_atomic_load(sp, __ATOMIC_RELAXED, __HIP_MEMORY_SCOPE_AGENT) < (u32)t) {}
      }
      __syncthreads();
    }
    if (t == 0 || rst){
      uint4 z; z.x=0u; z.y=0u; z.z=0u; z.w=0u;
      uint4* hd = (uint4*)&hHi[eb][scol];
      uint4* ld = (uint4*)&hLo[eb][scol];
      hd[0]=z;hd[1]=z;hd[2]=z;hd[3]=z;  ld[0]=z;ld[1]=z;ld[2]=z;ld[3]=z;
    } else {
      const u64* hrow64 = (const u64*)(hb_base + ((size_t)((t-1)&1)*16 + eb)*512 + scol);
      u32 hv[32];
      #pragma unroll
      for (int i=0;i<16;i++){
        u64 v = __hip_atomic_load(hrow64 + i, __ATOMIC_RELAXED, __HIP_MEMORY_SCOPE_AGENT);
        hv[2*i]   = (u32)v;
        hv[2*i+1] = (u32)(v >> 32);
      }
      u32 hiw[16], low[16];
      #pragma unroll
      for (int k=0;k<16;k++){
        hiw[k] = (hv[2*k] & 0xFFFFu) | (hv[2*k+1] << 16);
        low[k] = (hv[2*k] >> 16)     | (hv[2*k+1] & 0xFFFF0000u);
      }
      uint4* hd = (uint4*)&hHi[eb][scol];
      uint4* ld = (uint4*)&hLo[eb][scol];
      #pragma unroll
      for (int v=0;v<4;v++){
        uint4 hw; hw.x=hiw[4*v]; hw.y=hiw[4*v+1]; hw.z=hiw[4*v+2]; hw.w=hiw[4*v+3];
        uint4 lw; lw.x=low[4*v]; lw.y=low[4*v+1]; lw.z=low[4*v+2]; lw.w=low[4*v+3];
        hd[v]=hw; ld[v]=lw;
      }
    }
    __syncthreads();

    // h-part MFMAs: hHi*WhHi + hHi*WhLo + hLo*WhHi
    #pragma unroll
    for (int ktl=0;ktl<4;ktl++){
      const int ko = (wid*4+ktl)*32 + q*8;
      bf16x8 ahi = *(const bf16x8*)&hHi[n15][ko];
      bf16x8 alo = *(const bf16x8*)&hLo[n15][ko];
      #pragma unroll
      for (int gt=0;gt<4;gt++){
        acc[gt] = __builtin_amdgcn_mfma_f32_16x16x32_bf16(ahi, BW[1][ktl][gt], acc[gt], 0,0,0);
        acc[gt] = __builtin_amdgcn_mfma_f32_16x16x32_bf16(ahi, BW[2][ktl][gt], acc[gt], 0,0,0);
        acc[gt] = __builtin_amdgcn_mfma_f32_16x16x32_bf16(alo, BW[1][ktl][gt], acc[gt], 0,0,0);
      }
    }
    #pragma unroll
    for (int gt=0;gt<4;gt++)
      #pragma unroll
      for (int r=0;r<4;r++)
        gparts[wid][gt][q*4+r][n15] = acc[gt][r];
    __syncthreads();

    // ================= phase C: cell update + publish =================
    float gv[4];
    #pragma unroll
    for (int g=0;g<4;g++)
      gv[g] = gparts[0][g][eb][eu]+gparts[1][g][eb][eu]+gparts[2][g][eb][eu]+gparts[3][g][eb][eu]+biasr[g];
    float cp = cReg, hprev = hReg;
    if (rst){ cp = 0.0f; hprev = 0.0f; }
    float fg = sigm(gv[2] + 1.0f);
    float cn = fg*cp + sigm(gv[0])*tanh_f(gv[1]);
    float hn = sigm(gv[3])*tanh_f(cn);
    float ho = keepH ? hprev : hn;
    float co = keepC ? cp    : cn;
    cReg = co; hReg = ho;
    u16 hhi = f2bf(ho); u16 hlo = f2bf(ho - bf2f(hhi));
    u32 hp32 = ((u32)hlo<<16) | (u32)hhi;
    __hip_atomic_store(hb_base + ((size_t)(t&1)*16 + eb)*512 + (size_t)(ug*16+eu), hp32,
                       __ATOMIC_RELAXED, __HIP_MEMORY_SCOPE_AGENT);
    __syncthreads();   // drains vmcnt: write-through h stores are in LLC now
    if (tid == 0)
      __hip_atomic_store(stamps + ug, (u32)(t+1), __ATOMIC_RELAXED, __HIP_MEMORY_SCOPE_AGENT);
    out[outbase + ((size_t)tx << 10)] = ho;   // off the critical path
  }

  // ---- diagnostic channel: out[0] = 1000*code iff any self-test fired ----
  if (bx == 0 && tid == 0){
    u32 c = __hip_atomic_load(code, __ATOMIC_ACQUIRE, __HIP_MEMORY_SCOPE_AGENT);
    if (c != 0u) out[0] = 1000.0f * (float)c;
  }
}

extern "C" void kernel_launch(void* const* d_in, const int* in_sizes, int n_in,
                              void* d_out, int out_size, void* d_ws, size_t ws_size,
                              hipStream_t stream) {
  const int*   tokens  = (const int*)d_in[0];
  const int*   lengths = (const int*)d_in[1];
  const float* embed   = (const float*)d_in[2];
  const float* Wf      = (const float*)d_in[3];
  const float* bF      = (const float*)d_in[4];
  const float* Wb      = (const float*)d_in[5];
  const float* bB      = (const float*)d_in[6];
  float* out = (float*)d_out;

  const size_t SZ_WPACK = 16777216ull;
  const size_t SZ_X     = 67108864ull;
  const size_t SZ_HBUF  = 524288ull;
  const size_t SZ_CHK   = 65536ull;
  const size_t SZ_FLAGS = 32768ull;
  size_t need_full = SZ_WPACK + 2*SZ_X + SZ_HBUF + SZ_CHK + SZ_FLAGS + 128;
  int xsplit = (ws_size >= need_full) ? 1 : 0;

  char* p = (char*)d_ws;
  u16* wpack = (u16*)p;            p += SZ_WPACK;
  u16* X     = (u16*)p;            p += SZ_X;
  u16* XLO   = xsplit ? (u16*)p : X;
  if (xsplit)                      p += SZ_X;
  u32* hbuf  = (u32*)p;            p += SZ_HBUF;
  u32* chk   = (u32*)p;            p += SZ_CHK;
  u32* flags = (u32*)p;            p += SZ_FLAGS;
  u32* code  = (u32*)p;            p += 64;
  u32* keys  = (u32*)p;

  prep_k<<<dim3(4096), dim3(256), 0, stream>>>(Wf, Wb, wpack, flags, code, keys);
  embed_k<<<dim3(65536), dim3(256), 0, stream>>>(tokens, embed, keys, X, XLO, xsplit);
  lstm_k<<<dim3(256), dim3(256), 0, stream>>>(wpack, X, XLO, hbuf, chk, flags, code, keys,
                                              lengths, bF, bB, out, xsplit);
}

// Round 3
// 7379.419 us; speedup vs baseline: 2.1486x; 1.1082x over previous
//
#include <hip/hip_runtime.h>
#include <hip/hip_bf16.h>
#include <stdint.h>

typedef unsigned short u16;
typedef unsigned int   u32;
typedef unsigned long long u64;
typedef __bf16 bf16x8 __attribute__((ext_vector_type(8)));
typedef float  f32x4  __attribute__((ext_vector_type(4)));

__device__ __forceinline__ u32 rotl32(u32 v, int d){ return (v<<d)|(v>>(32-d)); }

// JAX threefry2x32: 20 rounds
__device__ __forceinline__ void tf2x32(u32 k0, u32 k1, u32 c0, u32 c1, u32 &o0, u32 &o1){
  u32 ks0=k0, ks1=k1, ks2=k0^k1^0x1BD11BDAu;
  u32 x0=c0+ks0, x1=c1+ks1;
  x0+=x1; x1=rotl32(x1,13); x1^=x0;  x0+=x1; x1=rotl32(x1,15); x1^=x0;
  x0+=x1; x1=rotl32(x1,26); x1^=x0;  x0+=x1; x1=rotl32(x1, 6); x1^=x0;
  x0+=ks1; x1+=ks2+1u;
  x0+=x1; x1=rotl32(x1,17); x1^=x0;  x0+=x1; x1=rotl32(x1,29); x1^=x0;
  x0+=x1; x1=rotl32(x1,16); x1^=x0;  x0+=x1; x1=rotl32(x1,24); x1^=x0;
  x0+=ks2; x1+=ks0+2u;
  x0+=x1; x1=rotl32(x1,13); x1^=x0;  x0+=x1; x1=rotl32(x1,15); x1^=x0;
  x0+=x1; x1=rotl32(x1,26); x1^=x0;  x0+=x1; x1=rotl32(x1, 6); x1^=x0;
  x0+=ks0; x1+=ks1+3u;
  x0+=x1; x1=rotl32(x1,17); x1^=x0;  x0+=x1; x1=rotl32(x1,29); x1^=x0;
  x0+=x1; x1=rotl32(x1,16); x1^=x0;  x0+=x1; x1=rotl32(x1,24); x1^=x0;
  x0+=ks1; x1+=ks2+4u;
  x0+=x1; x1=rotl32(x1,13); x1^=x0;  x0+=x1; x1=rotl32(x1,15); x1^=x0;
  x0+=x1; x1=rotl32(x1,26); x1^=x0;  x0+=x1; x1=rotl32(x1, 6); x1^=x0;
  x0+=ks2; x1+=ks0+5u;
  o0=x0; o1=x1;
}

__device__ __forceinline__ float u01(u32 b){ return __uint_as_float((b>>9)|0x3f800000u) - 1.0f; }
__device__ __forceinline__ u16 f2bf(float v){ __hip_bfloat16 h = __float2bfloat16(v); return *reinterpret_cast<u16*>(&h); }
__device__ __forceinline__ float bf2f(u16 b){ __hip_bfloat16 h; *reinterpret_cast<u16*>(&h)=b; return __bfloat162float(h); }
__device__ __forceinline__ float sigm(float x){ return 1.0f/(1.0f + __expf(-x)); }
__device__ __forceinline__ float tanh_f(float x){ return 1.0f - 2.0f/(__expf(2.0f*x) + 1.0f); }

// async global -> LDS DMA: HW writes (wave-uniform lds base) + lane*16
__device__ __forceinline__ void gload_lds16(const u16* g, u16* l){
  __builtin_amdgcn_global_load_lds(
      (const __attribute__((address_space(1))) unsigned int*)g,
      (__attribute__((address_space(3))) unsigned int*)l, 16, 0, 0);
}

// ---- kernel 1: weight packing (4 mats) + flag/code zero + PARTITIONABLE root split + KAT ----
extern "C" __global__ void __launch_bounds__(256) prep_k(
    const float* __restrict__ Wf, const float* __restrict__ Wb,
    u16* __restrict__ wpack, u32* __restrict__ flags, u32* __restrict__ code, u32* __restrict__ keys){
  u32 gid = blockIdx.x*256u + threadIdx.x;
  if (gid < 8192u) flags[gid] = 0u;
  if (gid == 0u){
    *code = 0u;
    u32 d0,d1,f0,f1,g0,g1;
    tf2x32(0u,42u, 0u,0u, d0,d1);   // kd = split(key(42),3)[0]
    tf2x32(0u,42u, 0u,1u, f0,f1);   // kf = [1]
    tf2x32(0u,42u, 0u,2u, g0,g1);   // kb = [2]
    keys[0]=d0; keys[1]=d1; keys[2]=f0; keys[3]=f1; keys[4]=g0; keys[5]=g1;
  }
  if (gid == 1u){
    u32 r0,r1; bool ok = true;
    tf2x32(0u,0u,0u,0u,r0,r1);
    ok = ok && (r0==0x6b200159u) && (r1==0x99ba4efeu);
    tf2x32(0x13198a2eu,0x03707344u,0x243f6a88u,0x85a308d3u,r0,r1);
    ok = ok && (r0==0xc4923a9cu) && (r1==0x483df7a0u);
    tf2x32(0xffffffffu,0xffffffffu,0xffffffffu,0xffffffffu,r0,r1);
    ok = ok && (r0==0x1cb996fcu) && (r1==0xbb002be7u);
    if (!ok) __hip_atomic_fetch_or(code, 4u, __ATOMIC_RELAXED, __HIP_MEMORY_SCOPE_AGENT);
  }
  u32 idx = gid >> 6, lane = gid & 63u;
  u32 mat = idx & 3u; u32 r = idx >> 2;
  u32 gt = r & 3u; r >>= 2;
  u32 kt = r & 15u; r >>= 4;
  u32 ug = r & 31u; u32 dir = r >> 5;
  u32 col = gt*512u + ug*16u + (lane & 15u);
  u32 kb  = kt*32u + ((lane>>4)<<3);
  const float* W = dir ? Wb : Wf;
  bool hrow = (mat==1u || mat==2u);
  bool lo   = (mat==2u || mat==3u);
  u16 o[8];
  #pragma unroll
  for (int j=0;j<8;j++){
    u32 k = kb + (u32)j;
    u32 row = hrow ? (512u + k) : k;
    float v = W[(size_t)row*2048u + col];
    u16 h = f2bf(v);
    o[j] = lo ? f2bf(v - bf2f(h)) : h;
  }
  u16* dst = wpack + ((size_t)idx*64u + lane)*8u;
  uint4 pk;
  pk.x = (u32)o[0] | ((u32)o[1]<<16);
  pk.y = (u32)o[2] | ((u32)o[3]<<16);
  pk.z = (u32)o[4] | ((u32)o[5]<<16);
  pk.w = (u32)o[6] | ((u32)o[7]<<16);
  *(uint4*)dst = pk;
}

// ---- kernel 2: embedding + dropout ----
extern "C" __global__ void __launch_bounds__(256) embed_k(
    const int* __restrict__ tokens, const float* __restrict__ emb,
    const u32* __restrict__ keys, u16* __restrict__ X, u16* __restrict__ XLO, int xsplit){
  u32 gid = blockIdx.x*256u + threadIdx.x;
  u32 kd0 = keys[0], kd1 = keys[1];
  u32 i0 = gid << 1;
  u32 a0,a1,b0,b1;
  tf2x32(kd0,kd1, 0u, i0,     a0,a1);
  tf2x32(kd0,kd1, 0u, i0|1u,  b0,b1);
  u32 bb = i0 >> 19, l = (i0 >> 9) & 1023u, d = i0 & 511u;
  int tok = tokens[(bb<<10)|l];
  const float* ep = emb + (size_t)(u32)tok*512u + d;
  float e0 = ep[0], e1 = ep[1];
  float v0 = (u01(a0^a1) < 0.9f) ? (e0/0.9f) : 0.0f;
  float v1 = (u01(b0^b1) < 0.9f) ? (e1/0.9f) : 0.0f;
  size_t off = (((size_t)l<<6)|bb)*512u + d;
  u16 h0 = f2bf(v0), h1 = f2bf(v1);
  *(u32*)(X+off) = (u32)h0 | ((u32)h1<<16);
  if (xsplit){
    u16 l0 = f2bf(v0 - bf2f(h0)), l1 = f2bf(v1 - bf2f(h1));
    *(u32*)(XLO+off) = (u32)l0 | ((u32)l1<<16);
  }
}

// ---- kernel 3: persistent bidirectional LSTM ----
// Zero cache-maintenance protocol (round 2) + latency-overlap pipeline (round 3):
//  - x double-buffered in LDS via global_load_lds DMA, prefetched one step ahead
//  - poll on wave3 || keychain on wave0
//  - h LLC loads issued first; zoneout threefry + x-MFMAs run under the h latency
//  - per-block stamps on private 128B lines (no false sharing)
extern "C" __global__ void __launch_bounds__(256,1) lstm_k(
    const u16* __restrict__ wpack, const u16* __restrict__ X, const u16* __restrict__ XLO,
    u32* hbuf, u32* chk, u32* flags, u32* code, const u32* __restrict__ keys,
    const int* __restrict__ lengths, const float* __restrict__ bF, const float* __restrict__ bB,
    float* __restrict__ out, int xsplit){
  __shared__ u16 xHi[2][16][520];
  __shared__ u16 xLoS[2][16][520];
  __shared__ u16 hHi[16][520];
  __shared__ u16 hLo[16][520];
  __shared__ float gparts[4][4][16][17];
  __shared__ u32 kzS[2];
  (void)chk;

  const int tid  = threadIdx.x;
  const int wid  = tid >> 6;
  const int lane = tid & 63;
  const int q    = lane >> 4, n15 = lane & 15;
  const int bx   = blockIdx.x;
  const int dir  = (bx & 7) >> 2, bg = bx & 3, ug = bx >> 3;
  const int grp  = dir*4 + bg;
  const int eb   = tid >> 4, eu = tid & 15;
  const int scol = eu * 32;

  // ---- self-test: MFMA A/B/C-D layout (bx0, wave0) ----
  if (bx == 0 && wid == 0){
    bf16x8 aI, aI2, bT;
    #pragma unroll
    for (int j=0;j<8;j++){
      int k = q*8 + j;
      aI[j]  = (__bf16)((k == n15)    ? 1.0f : 0.0f);
      aI2[j] = (__bf16)((k == n15+16) ? 1.0f : 0.0f);
      bT[j]  = (__bf16)((float)((k & 15)*16 + n15));
    }
    f32x4 z = {0.0f,0.0f,0.0f,0.0f};
    f32x4 d1 = __builtin_amdgcn_mfma_f32_16x16x32_bf16(aI,  bT, z, 0,0,0);
    f32x4 d2 = __builtin_amdgcn_mfma_f32_16x16x32_bf16(aI2, bT, z, 0,0,0);
    bool ok = true;
    #pragma unroll
    for (int r=0;r<4;r++){
      float ex = (float)((q*4 + r)*16 + n15);
      ok = ok && (d1[r] == ex) && (d2[r] == ex);
    }
    if (__any(ok ? 0 : 1) && lane == 0)
      __hip_atomic_fetch_or(code, 1u, __ATOMIC_RELAXED, __HIP_MEMORY_SCOPE_AGENT);
  }

  u32 kc0 = keys[2 + dir*2], kc1 = keys[3 + dir*2];

  bf16x8 BW[4][4][4];   // [mat][ktl][gt]  0=WxHi 1=WhHi 2=WhLo 3=WxLo
  #pragma unroll
  for (int ktl=0;ktl<4;ktl++)
    #pragma unroll
    for (int gt=0;gt<4;gt++)
      #pragma unroll
      for (int mat=0;mat<4;mat++){
        size_t idx = ((((size_t)(dir*32+ug)*16 + (size_t)(wid*4+ktl))*4 + gt)*4 + mat);
        BW[mat][ktl][gt] = *(const bf16x8*)(wpack + (idx*64 + lane)*8);
      }

  const float* bias = dir ? bB : bF;
  float biasr[4];
  #pragma unroll
  for (int g=0;g<4;g++) biasr[g] = bias[g*512 + ug*16 + eu];
  const int lenb = lengths[bg*16 + eb];

  float cReg = 0.0f, hReg = 0.0f;

  u32* hb_base = hbuf + (size_t)grp*2*16*512;
  const size_t outbase = (size_t)(bg*16+eb)*1048576 + (size_t)(dir*512 + ug*16 + eu);

  // ---- prologue: DMA x(0) into buffer 0 ----
  {
    const int tx0 = dir ? 1023 : 0;
    #pragma unroll
    for (int j=0;j<4;j++){
      const int rb = wid*4 + j;
      const size_t go = (((size_t)tx0*64) + (size_t)(bg*16 + rb))*512 + (size_t)lane*8;
      gload_lds16(X + go, &xHi[0][rb][0]);
      if (xsplit) gload_lds16(XLO + go, &xLoS[0][rb][0]);
    }
  }

  for (int t=0; t<1024; ++t){
    const int cur = t & 1, nxt = cur ^ 1;
    const int tx = dir ? (1023 - t) : t;

    // ================= P0: poll (wave3) || keychain (wave0) =================
    if (wid == 0){
      u32 A0,A1,B0,B1;
      tf2x32(kc0,kc1, 0u,0u, A0,A1);
      tf2x32(kc0,kc1, 0u,1u, B0,B1);
      if (lane==0){ kzS[0]=A0; kzS[1]=A1; }
      kc0=B0; kc1=B1;
    }
    if (t > 0 && wid == 3 && lane < 32){
      const u32* sp = flags + (((size_t)grp*32 + (u32)lane) << 5);
      while (__hip_atomic_load(sp, __ATOMIC_RELAXED, __HIP_MEMORY_SCOPE_AGENT) < (u32)t) {}
    }
    __syncthreads();   // stamps confirmed; kzS visible; x DMA for this step drained

    // ================= P1: h loads in flight under threefry + x-MFMA =================
    const bool rst = (dir==1) && (t > 1024 - lenb);
    const bool hload = (t > 0) && !rst;
    u64 hv64[16];
    if (hload){
      const u64* hrow64 = (const u64*)(hb_base + ((size_t)((t-1)&1)*16 + eb)*512 + scol);
      #pragma unroll
      for (int i=0;i<16;i++)
        hv64[i] = __hip_atomic_load(hrow64 + i, __ATOMIC_RELAXED, __HIP_MEMORY_SCOPE_AGENT);
    }
    // x(t+1) prefetch DMA — issued after h loads so the h wait is a counted vmcnt
    if (t < 1023){
      const int txn = dir ? (1022 - t) : (t + 1);
      #pragma unroll
      for (int j=0;j<4;j++){
        const int rb = wid*4 + j;
        const size_t go = (((size_t)txn*64) + (size_t)(bg*16 + rb))*512 + (size_t)lane*8;
        gload_lds16(X + go, &xHi[nxt][rb][0]);
        if (xsplit) gload_lds16(XLO + go, &xLoS[nxt][rb][0]);
      }
    }
    // zoneout bits (VALU, under h latency)
    const u32 cnt = (u32)((bg*16+eb)*512 + ug*16+eu);
    u32 p0,p1,q0,q1;
    tf2x32(kzS[0], kzS[1], 0u, cnt,          p0,p1);
    tf2x32(kzS[0], kzS[1], 0u, cnt+32768u,   q0,q1);
    const bool keepH = (u01(p0^p1) < 0.1f);
    const bool keepC = (u01(q0^q1) < 0.1f);

    // x-part MFMAs (under h latency): xHi*WxHi + xHi*WxLo (+ xLo*WxHi)
    f32x4 zz = {0.0f,0.0f,0.0f,0.0f};
    f32x4 acc[4] = {zz,zz,zz,zz};
    #pragma unroll
    for (int ktl=0;ktl<4;ktl++){
      const int ko = (wid*4+ktl)*32 + q*8;
      bf16x8 ax = *(const bf16x8*)&xHi[cur][n15][ko];
      #pragma unroll
      for (int gt=0;gt<4;gt++){
        acc[gt] = __builtin_amdgcn_mfma_f32_16x16x32_bf16(ax, BW[0][ktl][gt], acc[gt], 0,0,0);
        acc[gt] = __builtin_amdgcn_mfma_f32_16x16x32_bf16(ax, BW[3][ktl][gt], acc[gt], 0,0,0);
      }
      if (xsplit){
        bf16x8 axl = *(const bf16x8*)&xLoS[cur][n15][ko];
        #pragma unroll
        for (int gt=0;gt<4;gt++)
          acc[gt] = __builtin_amdgcn_mfma_f32_16x16x32_bf16(axl, BW[0][ktl][gt], acc[gt], 0,0,0);
      }
    }

    // h staging (unpack waits on the h loads only)
    if (!hload){
      uint4 z; z.x=0u; z.y=0u; z.z=0u; z.w=0u;
      uint4* hd = (uint4*)&hHi[eb][scol];
      uint4* ld = (uint4*)&hLo[eb][scol];
      hd[0]=z;hd[1]=z;hd[2]=z;hd[3]=z;  ld[0]=z;ld[1]=z;ld[2]=z;ld[3]=z;
    } else {
      u32 hiw[16], low[16];
      #pragma unroll
      for (int k=0;k<16;k++){
        u32 lo32 = (u32)hv64[k], hi32 = (u32)(hv64[k] >> 32);
        hiw[k] = (lo32 & 0xFFFFu) | (hi32 << 16);
        low[k] = (lo32 >> 16)     | (hi32 & 0xFFFF0000u);
      }
      uint4* hd = (uint4*)&hHi[eb][scol];
      uint4* ld = (uint4*)&hLo[eb][scol];
      #pragma unroll
      for (int v=0;v<4;v++){
        uint4 hw; hw.x=hiw[4*v]; hw.y=hiw[4*v+1]; hw.z=hiw[4*v+2]; hw.w=hiw[4*v+3];
        uint4 lw; lw.x=low[4*v]; lw.y=low[4*v+1]; lw.z=low[4*v+2]; lw.w=low[4*v+3];
        hd[v]=hw; ld[v]=lw;
      }
    }
    __syncthreads();

    // ================= P2: h-part MFMAs =================
    #pragma unroll
    for (int ktl=0;ktl<4;ktl++){
      const int ko = (wid*4+ktl)*32 + q*8;
      bf16x8 ahi = *(const bf16x8*)&hHi[n15][ko];
      bf16x8 alo = *(const bf16x8*)&hLo[n15][ko];
      #pragma unroll
      for (int gt=0;gt<4;gt++){
        acc[gt] = __builtin_amdgcn_mfma_f32_16x16x32_bf16(ahi, BW[1][ktl][gt], acc[gt], 0,0,0);
        acc[gt] = __builtin_amdgcn_mfma_f32_16x16x32_bf16(ahi, BW[2][ktl][gt], acc[gt], 0,0,0);
        acc[gt] = __builtin_amdgcn_mfma_f32_16x16x32_bf16(alo, BW[1][ktl][gt], acc[gt], 0,0,0);
      }
    }
    #pragma unroll
    for (int gt=0;gt<4;gt++)
      #pragma unroll
      for (int r=0;r<4;r++)
        gparts[wid][gt][q*4+r][n15] = acc[gt][r];
    __syncthreads();

    // ================= P3: cell update + publish =================
    float gv[4];
    #pragma unroll
    for (int g=0;g<4;g++)
      gv[g] = gparts[0][g][eb][eu]+gparts[1][g][eb][eu]+gparts[2][g][eb][eu]+gparts[3][g][eb][eu]+biasr[g];
    float cp = cReg, hprev = hReg;
    if (rst){ cp = 0.0f; hprev = 0.0f; }
    float fg = sigm(gv[2] + 1.0f);
    float cn = fg*cp + sigm(gv[0])*tanh_f(gv[1]);
    float hn = sigm(gv[3])*tanh_f(cn);
    float ho = keepH ? hprev : hn;
    float co = keepC ? cp    : cn;
    cReg = co; hReg = ho;
    u16 hhi = f2bf(ho); u16 hlo = f2bf(ho - bf2f(hhi));
    u32 hp32 = ((u32)hlo<<16) | (u32)hhi;
    __hip_atomic_store(hb_base + ((size_t)(t&1)*16 + eb)*512 + (size_t)(ug*16+eu), hp32,
                       __ATOMIC_RELAXED, __HIP_MEMORY_SCOPE_AGENT);
    __syncthreads();   // drains vmcnt: write-through h stores are in LLC now
    if (tid == 0)
      __hip_atomic_store(flags + (((size_t)grp*32 + ug) << 5), (u32)(t+1),
                         __ATOMIC_RELAXED, __HIP_MEMORY_SCOPE_AGENT);
    out[outbase + ((size_t)tx << 10)] = ho;   // off the critical path
  }

  // ---- diagnostic channel ----
  if (bx == 0 && tid == 0){
    u32 c = __hip_atomic_load(code, __ATOMIC_ACQUIRE, __HIP_MEMORY_SCOPE_AGENT);
    if (c != 0u) out[0] = 1000.0f * (float)c;
  }
}

extern "C" void kernel_launch(void* const* d_in, const int* in_sizes, int n_in,
                              void* d_out, int out_size, void* d_ws, size_t ws_size,
                              hipStream_t stream) {
  const int*   tokens  = (const int*)d_in[0];
  const int*   lengths = (const int*)d_in[1];
  const float* embed   = (const float*)d_in[2];
  const float* Wf      = (const float*)d_in[3];
  const float* bF      = (const float*)d_in[4];
  const float* Wb      = (const float*)d_in[5];
  const float* bB      = (const float*)d_in[6];
  float* out = (float*)d_out;

  const size_t SZ_WPACK = 16777216ull;
  const size_t SZ_X     = 67108864ull;
  const size_t SZ_HBUF  = 524288ull;
  const size_t SZ_CHK   = 65536ull;
  const size_t SZ_FLAGS = 32768ull;
  size_t need_full = SZ_WPACK + 2*SZ_X + SZ_HBUF + SZ_CHK + SZ_FLAGS + 128;
  int xsplit = (ws_size >= need_full) ? 1 : 0;

  char* p = (char*)d_ws;
  u16* wpack = (u16*)p;            p += SZ_WPACK;
  u16* X     = (u16*)p;            p += SZ_X;
  u16* XLO   = xsplit ? (u16*)p : X;
  if (xsplit)                      p += SZ_X;
  u32* hbuf  = (u32*)p;            p += SZ_HBUF;
  u32* chk   = (u32*)p;            p += SZ_CHK;
  u32* flags = (u32*)p;            p += SZ_FLAGS;
  u32* code  = (u32*)p;            p += 64;
  u32* keys  = (u32*)p;

  prep_k<<<dim3(4096), dim3(256), 0, stream>>>(Wf, Wb, wpack, flags, code, keys);
  embed_k<<<dim3(65536), dim3(256), 0, stream>>>(tokens, embed, keys, X, XLO, xsplit);
  lstm_k<<<dim3(256), dim3(256), 0, stream>>>(wpack, X, XLO, hbuf, chk, flags, code, keys,
                                              lengths, bF, bB, out, xsplit);
}